// Round 1
// baseline (880.341 us; speedup 1.0000x reference)
//
#include <hip/hip_runtime.h>

// Problem dims
#define V_SZ 50000
#define E_SZ 256
#define H_SZ 512
#define B_SZ 64
#define T_SZ 2048

// d_out offsets (floats): logits | h_new | c_new | attn
#define H_OFF    (B_SZ * V_SZ)
#define C_OFF    (H_OFF + B_SZ * H_SZ)
#define ATTN_OFF (C_OFF + B_SZ * H_SZ)

// ws layout (floats) — all regions fully written before read; no memset needed
#define WS_X    0                         // [B][768]  x = [embedded(256) | context(512)]
#define WS_HW   (WS_X + B_SZ * 768)       // [B][512]  h @ W_dec^T
#define WS_SC   (WS_HW + B_SZ * H_SZ)     // [B][T] scores (full, single copy)
#define WS_CTXP (WS_SC + B_SZ * T_SZ)     // [16][B][512] context partials
#define WS_X2   (WS_CTXP + 16 * B_SZ * H_SZ) // [B][1024] x2 = [h_new | context]
#define WS_GP   (WS_X2 + B_SZ * 1024)     // [8][B][2048] gate partials
#define WS_WB   (WS_GP + 8 * B_SZ * 2048) // W_enc as bf16, sliced layout: 512*512 ushort
// total = 1,982,464 floats ≈ 7.9 MB

typedef __attribute__((ext_vector_type(8))) short bf16x8;
typedef __attribute__((ext_vector_type(4))) float floatx4;

__device__ __forceinline__ float fast_tanh(float x) {
    return 1.f - 2.f / (__expf(2.f * x) + 1.f);
}
__device__ __forceinline__ float fast_sigmoid(float x) {
    return 1.f / (1.f + __expf(-x));
}
__device__ __forceinline__ unsigned short f2bf(float f) {
    union { float f; unsigned u; } v; v.f = f;
    unsigned r = v.u + 0x7FFFu + ((v.u >> 16) & 1u);  // RTN-even
    return (unsigned short)(r >> 16);
}

// pack 8 fp32 -> 8 bf16 via v_cvt_pk_bf16_f32 (RNE, 1 instr per 2 elements)
__device__ __forceinline__ bf16x8 cvt8(float4 a, float4 b) {
    union { unsigned u[4]; bf16x8 v; } r;
    asm("v_cvt_pk_bf16_f32 %0, %1, %2" : "=v"(r.u[0]) : "v"(a.x), "v"(a.y));
    asm("v_cvt_pk_bf16_f32 %0, %1, %2" : "=v"(r.u[1]) : "v"(a.z), "v"(a.w));
    asm("v_cvt_pk_bf16_f32 %0, %1, %2" : "=v"(r.u[2]) : "v"(b.x), "v"(b.y));
    asm("v_cvt_pk_bf16_f32 %0, %1, %2" : "=v"(r.u[3]) : "v"(b.z), "v"(b.w));
    return r.v;
}

// async global->LDS, 16B per lane. LDS dest must be linear (uniform base + lane*16).
__device__ __forceinline__ void async_copy16(void* lds, const void* g) {
    __builtin_amdgcn_global_load_lds(
        (const __attribute__((address_space(1))) unsigned int*)g,
        (__attribute__((address_space(3))) unsigned int*)lds, 16, 0, 0);
}

// K0: W_enc (512x512 fp32) -> Wb bf16, per-K-slice swizzled layout.
// Layout: slice s = k>>5 (32-k slices, 32KB each, contiguous). Within a slice,
// 16B unit (j, q=(k>>3)&3) lives at unit index u = 4*j + ((q + j) & 3).
// This makes the linear global_load_lds image conflict-minimal for the
// ds_read_b128 frag pattern in K2 (8 lanes per 4-bank group = b128 minimum).
__global__ void k0_wenc_bf16(const float* __restrict__ W_enc, float* __restrict__ ws) {
    unsigned short* Wb = (unsigned short*)(ws + WS_WB);
    const int id = blockIdx.x * 256 + threadIdx.x;  // 128 blocks x 256 = 32768
    const int j = id >> 6, kc = id & 63;            // kc = 8-float chunk
    const int k = kc * 8;
    float4 a = *(const float4*)(W_enc + j * 512 + k);
    float4 b4 = *(const float4*)(W_enc + j * 512 + k + 4);
    ushort4 lo = {f2bf(a.x), f2bf(a.y), f2bf(a.z), f2bf(a.w)};
    ushort4 hi = {f2bf(b4.x), f2bf(b4.y), f2bf(b4.z), f2bf(b4.w)};
    const int s = kc >> 2, q = kc & 3;
    const int u = 4 * j + ((q + j) & 3);
    unsigned short* dst = Wb + s * 16384 + u * 8;
    *(ushort4*)(dst) = lo;
    *(ushort4*)(dst + 4) = hi;
}

// K1: embedded = emb[token] -> x[:, :256];  hW = h @ W_dec^T
__global__ void k1_embed_hw(const int* __restrict__ tok, const float* __restrict__ hidden,
                            const float* __restrict__ emb, const float* __restrict__ W_dec,
                            float* __restrict__ ws) {
    const int b = blockIdx.x, tid = threadIdx.x;
    __shared__ __align__(16) float sh[512];
    sh[tid]       = hidden[b * 512 + tid];
    sh[tid + 256] = hidden[b * 512 + tid + 256];
    const int t = tok[b];
    ws[WS_X + b * 768 + tid] = emb[t * 256 + tid];
    __syncthreads();
    for (int jr = tid; jr < 512; jr += 256) {
        const float* w = W_dec + jr * 512;
        float acc = 0.f;
        #pragma unroll 8
        for (int k = 0; k < 512; k += 4) {
            float4 wv = *(const float4*)(w + k);
            float4 hv = *(const float4*)(sh + k);
            acc += wv.x * hv.x + wv.y * hv.y + wv.z * hv.z + wv.w * hv.w;
        }
        ws[WS_HW + b * 512 + jr] = acc;
    }
}

// K2: scores via bf16 MFMA. Block tile: M=64 t-rows x N=512 j x K=512, BK=32.
// A: per-wave register loads straight from enc (fp32) + cvt_pk to bf16 frags,
//    1-step register prefetch. No LDS for A.
// B: LDS double-buffered 32KB slices staged with global_load_lds dwordx4 from
//    the pre-swizzled Wb layout (K0). One barrier per K-step; next-step B stage
//    and A loads stay in flight across the whole compute phase.
// Epilogue: tanh + v-dot + quad-lane reduce + cross-wave LDS reduce.
__global__ __launch_bounds__(256, 2)
void k2_scores(const float* __restrict__ enc, const float* __restrict__ v_attn,
               float* __restrict__ ws) {
    __shared__ __align__(16) unsigned short Bs[2][16384];  // 2 x 32KB K-slices
    __shared__ float sp[4][64];
    const unsigned short* Wb = (const unsigned short*)(ws + WS_WB);
    const int tid = threadIdx.x;
    const int lane = tid & 63, wv = tid >> 6;
    const int lane15 = lane & 15, quad = lane >> 4;
    const int t0 = blockIdx.x * 64, b = blockIdx.y;
    const int wn = wv * 128;

    // A source: row = b*2048 + t0 + mt*16 + lane15, k = kt + quad*8 (8 contiguous fp32)
    const float* aBase = enc + ((size_t)(b * 2048 + t0 + lane15)) * 512 + quad * 8;

    // B frag LDS byte offset (within slice): 64*j + 16*((quad + j)&3), j = wn + nt*16 + lane15
    const int j0 = wn + lane15;
    const int rdBase = 64 * j0 + 16 * ((quad + j0) & 3);  // + nt*1024

    floatx4 acc[4][8];
    #pragma unroll
    for (int mt = 0; mt < 4; mt++)
        #pragma unroll
        for (int nt = 0; nt < 8; nt++) acc[mt][nt] = (floatx4){0.f, 0.f, 0.f, 0.f};

    float4 aF[4][2];
    // prologue: stage slice 0, load A[0]
    {
        const char* gs = (const char*)Wb;  // slice 0
        #pragma unroll
        for (int q8 = 0; q8 < 8; ++q8)
            async_copy16((char*)&Bs[0][0] + q8 * 4096 + tid * 16, gs + q8 * 4096 + tid * 16);
        #pragma unroll
        for (int mt = 0; mt < 4; ++mt) {
            aF[mt][0] = *(const float4*)(aBase + mt * 8192);
            aF[mt][1] = *(const float4*)(aBase + mt * 8192 + 4);
        }
    }
    __syncthreads();

    for (int t = 0; t < 16; ++t) {
        const int cur = t & 1;
        // 1) stage next B slice into the other buffer (in flight through compute)
        if (t < 15) {
            char* nb = (char*)&Bs[cur ^ 1][0];
            const char* gs = (const char*)(Wb + (t + 1) * 16384);
            #pragma unroll
            for (int q8 = 0; q8 < 8; ++q8)
                async_copy16(nb + q8 * 4096 + tid * 16, gs + q8 * 4096 + tid * 16);
        }
        // 2) convert A[t] (regs loaded last iter, completed at last barrier)
        bf16x8 af[4];
        #pragma unroll
        for (int mt = 0; mt < 4; ++mt) af[mt] = cvt8(aF[mt][0], aF[mt][1]);
        // 3) prefetch A[t+1] into the now-free fp32 regs
        if (t < 15) {
            const float* ab = aBase + (t + 1) * 32;
            #pragma unroll
            for (int mt = 0; mt < 4; ++mt) {
                aF[mt][0] = *(const float4*)(ab + mt * 8192);
                aF[mt][1] = *(const float4*)(ab + mt * 8192 + 4);
            }
        }
        // 4) compute on current slice
        const char* bs = (const char*)&Bs[cur][0];
        #pragma unroll
        for (int nt = 0; nt < 8; ++nt) {
            bf16x8 bfr = *(const bf16x8*)(bs + rdBase + nt * 1024);
            #pragma unroll
            for (int mt = 0; mt < 4; ++mt)
                acc[mt][nt] = __builtin_amdgcn_mfma_f32_16x16x32_bf16(af[mt], bfr, acc[mt][nt], 0, 0, 0);
        }
        __syncthreads();  // drains next-slice stage + A prefetch; swaps buffers
    }

    // epilogue
    float vj[8], hwj[8];
    #pragma unroll
    for (int nt = 0; nt < 8; nt++) {
        int jg = wn + nt * 16 + lane15;
        vj[nt] = v_attn[jg];
        hwj[nt] = ws[WS_HW + b * 512 + jg];
    }
    #pragma unroll
    for (int mt = 0; mt < 4; mt++) {
        #pragma unroll
        for (int reg = 0; reg < 4; reg++) {
            int row = mt * 16 + quad * 4 + reg;
            float s = 0.f;
            #pragma unroll
            for (int nt = 0; nt < 8; nt++)
                s += vj[nt] * fast_tanh(acc[mt][nt][reg] + hwj[nt]);
            #pragma unroll
            for (int off = 8; off; off >>= 1) s += __shfl_xor(s, off);
            if (lane15 == 0) sp[wv][row] = s;
        }
    }
    __syncthreads();
    if (tid < 64)
        ws[WS_SC + b * 2048 + t0 + tid] = sp[0][tid] + sp[1][tid] + sp[2][tid] + sp[3][tid];
}

// K3: softmax over T per b; writes attn to d_out
__global__ void k3_softmax(const float* __restrict__ ws, float* __restrict__ out) {
    const int b = blockIdx.x, tid = threadIdx.x;
    const float* s0 = ws + WS_SC + b * 2048;
    float sv[8];
    float m = -1e30f;
    #pragma unroll
    for (int i = 0; i < 8; i++) {
        int t = tid + 256 * i;
        sv[i] = s0[t];
        m = fmaxf(m, sv[i]);
    }
    #pragma unroll
    for (int o = 32; o; o >>= 1) m = fmaxf(m, __shfl_xor(m, o, 64));
    __shared__ float red[4], red2[4];
    if ((tid & 63) == 0) red[tid >> 6] = m;
    __syncthreads();
    m = fmaxf(fmaxf(red[0], red[1]), fmaxf(red[2], red[3]));
    float sum = 0.f;
    #pragma unroll
    for (int i = 0; i < 8; i++) { sv[i] = __expf(sv[i] - m); sum += sv[i]; }
    #pragma unroll
    for (int o = 32; o; o >>= 1) sum += __shfl_xor(sum, o, 64);
    if ((tid & 63) == 0) red2[tid >> 6] = sum;
    __syncthreads();
    sum = red2[0] + red2[1] + red2[2] + red2[3];
    const float inv = 1.f / sum;
    #pragma unroll
    for (int i = 0; i < 8; i++) {
        int t = tid + 256 * i;
        out[ATTN_OFF + b * 2048 + t] = sv[i] * inv;
    }
}

// K4: context partials over t-chunks of 128
__global__ void k4_ctx(const float* __restrict__ enc, const float* __restrict__ attn_out,
                       float* __restrict__ ws) {
    const int ts = blockIdx.x, b = blockIdx.y, tid = threadIdx.x;
    const float* attn = attn_out + ATTN_OFF + b * 2048 + ts * 128;
    const float* ep = enc + (size_t)(b * 2048 + ts * 128) * 512 + tid * 2;
    float2 acc = {0.f, 0.f};
    #pragma unroll 4
    for (int tt = 0; tt < 128; tt++) {
        float a = attn[tt];
        float2 e = *(const float2*)(ep + (size_t)tt * 512);
        acc.x += a * e.x;
        acc.y += a * e.y;
    }
    *(float2*)(ws + WS_CTXP + (ts * 64 + b) * 512 + tid * 2) = acc;
}

// K4b: reduce 16 context partials -> x[:,256:768] and x2[:,512:1024]
__global__ void k4b_ctx_reduce(float* __restrict__ ws) {
    const int idx = blockIdx.x * 256 + threadIdx.x;
    const int b = idx >> 9, h = idx & 511;
    float s = 0.f;
    #pragma unroll
    for (int c = 0; c < 16; c++) s += ws[WS_CTXP + c * (B_SZ * 512) + b * 512 + h];
    ws[WS_X + b * 768 + 256 + h] = s;
    ws[WS_X2 + b * 1024 + 512 + h] = s;
}

// K5: gate partials (fp32 register-tiled GEMM, small: 64x2048x1280)
__global__ __launch_bounds__(256, 2)
void k5_gates(const float* __restrict__ hidden, const float* __restrict__ W_ih,
              const float* __restrict__ W_hh, float* __restrict__ ws) {
    __shared__ __align__(16) float Wg[128 * 12];
    __shared__ __align__(16) float Zs[64 * 8];
    const int tid = threadIdx.x;
    const int jb = tid & 31, tg = tid >> 5;
    const int g0 = blockIdx.x * 128;
    const int kc = blockIdx.y;
    const int kbase = kc * 160;
    const float* xp = ws + WS_X;

    float acc[8][4];
    #pragma unroll
    for (int r = 0; r < 8; r++)
        #pragma unroll
        for (int j = 0; j < 4; j++) acc[r][j] = 0.f;

    for (int kt0 = 0; kt0 < 160; kt0 += 8) {
        const int kt = kbase + kt0;
        __syncthreads();
        {
            int row = tid >> 1, kq = tid & 1;
            int k = kt + kq * 4;
            const float* src = (k < 768) ? (W_ih + (g0 + row) * 768 + k)
                                         : (W_hh + (g0 + row) * 512 + (k - 768));
            *(float4*)(Wg + row * 12 + kq * 4) = *(const float4*)src;
        }
        if (tid < 128) {
            int row = tid >> 1, kq = tid & 1;
            int k = kt + kq * 4;
            const float* src = (k < 768) ? (xp + row * 768 + k)
                                         : (hidden + row * 512 + (k - 768));
            *(float4*)(Zs + row * 8 + kq * 4) = *(const float4*)src;
        }
        __syncthreads();

        float er[8][8];
        #pragma unroll
        for (int r = 0; r < 8; r++) {
            float4 a = *(const float4*)(Zs + (tg * 8 + r) * 8);
            float4 c = *(const float4*)(Zs + (tg * 8 + r) * 8 + 4);
            er[r][0] = a.x; er[r][1] = a.y; er[r][2] = a.z; er[r][3] = a.w;
            er[r][4] = c.x; er[r][5] = c.y; er[r][6] = c.z; er[r][7] = c.w;
        }
        #pragma unroll
        for (int jj = 0; jj < 4; jj++) {
            const float* wr = Wg + (jb + 32 * jj) * 12;
            float4 w0 = *(const float4*)(wr);
            float4 w1 = *(const float4*)(wr + 4);
            float w[8] = {w0.x, w0.y, w0.z, w0.w, w1.x, w1.y, w1.z, w1.w};
            #pragma unroll
            for (int r = 0; r < 8; r++)
                #pragma unroll
                for (int k = 0; k < 8; k++) acc[r][jj] += er[r][k] * w[k];
        }
    }
    #pragma unroll
    for (int jj = 0; jj < 4; jj++)
        #pragma unroll
        for (int r = 0; r < 8; r++)
            ws[WS_GP + kc * (B_SZ * 2048) + (tg * 8 + r) * 2048 + g0 + jb + 32 * jj] = acc[r][jj];
}

// K5b: sum gate partials + biases, LSTM pointwise
__global__ void k5b_lstm(const float* __restrict__ cell, const float* __restrict__ b_ih,
                         const float* __restrict__ b_hh, float* __restrict__ ws,
                         float* __restrict__ out) {
    const int e = blockIdx.x * 256 + threadIdx.x;
    const int b = e >> 9, hh = e & 511;
    float g4[4];
    #pragma unroll
    for (int q = 0; q < 4; q++) {
        float s = b_ih[q * 512 + hh] + b_hh[q * 512 + hh];
        #pragma unroll
        for (int c = 0; c < 8; c++)
            s += ws[WS_GP + c * (B_SZ * 2048) + b * 2048 + q * 512 + hh];
        g4[q] = s;
    }
    const float ig = fast_sigmoid(g4[0]);
    const float fg = fast_sigmoid(g4[1]);
    const float gg = fast_tanh(g4[2]);
    const float og = fast_sigmoid(g4[3]);
    const float c_old = cell[b * 512 + hh];
    const float c_new = fg * c_old + ig * gg;
    const float h_new = og * fast_tanh(c_new);
    out[H_OFF + b * 512 + hh] = h_new;
    out[C_OFF + b * 512 + hh] = c_new;
    ws[WS_X2 + b * 1024 + hh] = h_new;
}

// K6: logits via bf16 MFMA. Block tile M=64 b x N=256 v x K=1024, BK=32.
// W_out rows are read exactly once -> convert fp32->bf16 in-block.
__global__ __launch_bounds__(256, 2)
void k6_logits(const float* __restrict__ W_out, const float* __restrict__ b_out,
               const float* __restrict__ ws, float* __restrict__ out) {
    __shared__ __align__(16) unsigned short Xs[64 * 40];   // [b-row][k]
    __shared__ __align__(16) unsigned short Ws2[256 * 40]; // [v-row][k]
    const float* x2 = ws + WS_X2;
    const int tid = threadIdx.x;
    const int lane = tid & 63, wv = tid >> 6;
    const int lane15 = lane & 15, quad = lane >> 4;
    const int v0 = blockIdx.x * 256;
    const int wn = wv * 64;

    floatx4 acc[4][4];
    #pragma unroll
    for (int mt = 0; mt < 4; mt++)
        #pragma unroll
        for (int nt = 0; nt < 4; nt++) acc[mt][nt] = (floatx4){0.f, 0.f, 0.f, 0.f};

    for (int kt = 0; kt < 1024; kt += 32) {
        __syncthreads();
        #pragma unroll
        for (int q = 0; q < 2; q++) {  // x2 tile
            int f = tid + 256 * q;
            int row = f >> 3, kq = f & 7;
            float4 v = *(const float4*)(x2 + row * 1024 + kt + kq * 4);
            ushort4 h = {f2bf(v.x), f2bf(v.y), f2bf(v.z), f2bf(v.w)};
            *(ushort4*)(Xs + row * 40 + kq * 4) = h;
        }
        #pragma unroll
        for (int q = 0; q < 8; q++) {  // W_out tile (256 rows x 32 k)
            int f = tid + 256 * q;
            int row = f >> 3, kq = f & 7;
            int v = v0 + row; if (v > V_SZ - 1) v = V_SZ - 1;
            float4 w = *(const float4*)(W_out + (size_t)v * 1024 + kt + kq * 4);
            ushort4 h = {f2bf(w.x), f2bf(w.y), f2bf(w.z), f2bf(w.w)};
            *(ushort4*)(Ws2 + row * 40 + kq * 4) = h;
        }
        __syncthreads();

        bf16x8 af[4];
        #pragma unroll
        for (int mt = 0; mt < 4; mt++)
            af[mt] = *(const bf16x8*)(Xs + (mt * 16 + lane15) * 40 + quad * 8);
        #pragma unroll
        for (int nt = 0; nt < 4; nt++) {
            bf16x8 bf = *(const bf16x8*)(Ws2 + (wn + nt * 16 + lane15) * 40 + quad * 8);
            #pragma unroll
            for (int mt = 0; mt < 4; mt++)
                acc[mt][nt] = __builtin_amdgcn_mfma_f32_16x16x32_bf16(af[mt], bf, acc[mt][nt], 0, 0, 0);
        }
    }

    #pragma unroll
    for (int nt = 0; nt < 4; nt++) {
        const int v = v0 + wn + nt * 16 + lane15;
        if (v < V_SZ) {
            const float bo = b_out[v];
            #pragma unroll
            for (int mt = 0; mt < 4; mt++)
                #pragma unroll
                for (int reg = 0; reg < 4; reg++) {
                    const int br = mt * 16 + quad * 4 + reg;
                    out[br * V_SZ + v] = acc[mt][nt][reg] + bo;
                }
        }
    }
}

extern "C" void kernel_launch(void* const* d_in, const int* in_sizes, int n_in,
                              void* d_out, int out_size, void* d_ws, size_t ws_size,
                              hipStream_t stream) {
    (void)in_sizes; (void)n_in; (void)out_size; (void)ws_size;
    const int*   tok    = (const int*)d_in[0];
    const float* hidden = (const float*)d_in[1];
    const float* cell   = (const float*)d_in[2];
    const float* enc    = (const float*)d_in[3];
    const float* emb    = (const float*)d_in[4];
    const float* W_enc  = (const float*)d_in[5];
    const float* W_dec  = (const float*)d_in[6];
    const float* v_attn = (const float*)d_in[7];
    const float* W_ih   = (const float*)d_in[8];
    const float* W_hh   = (const float*)d_in[9];
    const float* b_ih   = (const float*)d_in[10];
    const float* b_hh   = (const float*)d_in[11];
    const float* W_out  = (const float*)d_in[12];
    const float* b_out  = (const float*)d_in[13];
    float* out = (float*)d_out;
    float* ws  = (float*)d_ws;

    k0_wenc_bf16<<<dim3(128), dim3(256), 0, stream>>>(W_enc, ws);
    k1_embed_hw<<<dim3(64), dim3(256), 0, stream>>>(tok, hidden, emb, W_dec, ws);
    k2_scores<<<dim3(32, 64), dim3(256), 0, stream>>>(enc, v_attn, ws);
    k3_softmax<<<dim3(64), dim3(256), 0, stream>>>(ws, out);
    k4_ctx<<<dim3(16, 64), dim3(256), 0, stream>>>(enc, out, ws);
    k4b_ctx_reduce<<<dim3(128), dim3(256), 0, stream>>>(ws);
    k5_gates<<<dim3(16, 8), dim3(256), 0, stream>>>(hidden, W_ih, W_hh, ws);
    k5b_lstm<<<dim3(128), dim3(256), 0, stream>>>(cell, b_ih, b_hh, ws, out);
    k6_logits<<<dim3(196), dim3(256), 0, stream>>>(W_out, b_out, ws, out);
}

// Round 4
// 685.711 us; speedup vs baseline: 1.2838x; 1.2838x over previous
//
#include <hip/hip_runtime.h>

// Problem dims
#define V_SZ 50000
#define E_SZ 256
#define H_SZ 512
#define B_SZ 64
#define T_SZ 2048

// d_out offsets (floats): logits | h_new | c_new | attn
#define H_OFF    (B_SZ * V_SZ)
#define C_OFF    (H_OFF + B_SZ * H_SZ)
#define ATTN_OFF (C_OFF + B_SZ * H_SZ)

// ws layout (floats)
#define WS_X    0                         // [B][768]  x = [embedded(256) | context(512)]
#define WS_HW   (WS_X + B_SZ * 768)       // [B][512]  h @ W_dec^T
#define WS_SC   (WS_HW + B_SZ * H_SZ)     // [B][T] scores
#define WS_CTXP (WS_SC + B_SZ * T_SZ)     // [16][B][512] context partials
#define WS_X2   (WS_CTXP + 16 * B_SZ * H_SZ) // [B][1024] fp32 x2 = [h_new | context]
#define WS_GP   (WS_X2 + B_SZ * 1024)     // [8][B][2048] gate partials
#define WS_WB   (WS_GP + 8 * B_SZ * 2048) // W_enc bf16, K-slice swizzled: 512*512 ushort

typedef __attribute__((ext_vector_type(8))) short bf16x8;
typedef __attribute__((ext_vector_type(4))) float floatx4;

__device__ __forceinline__ float fast_tanh(float x) {
    return 1.f - 2.f / (__expf(2.f * x) + 1.f);
}
__device__ __forceinline__ float fast_sigmoid(float x) {
    return 1.f / (1.f + __expf(-x));
}
__device__ __forceinline__ unsigned short f2bf(float f) {
    union { float f; unsigned u; } v; v.f = f;
    unsigned r = v.u + 0x7FFFu + ((v.u >> 16) & 1u);  // RTN-even
    return (unsigned short)(r >> 16);
}

// pack 8 fp32 -> 8 bf16 via v_cvt_pk_bf16_f32 (RNE, 1 instr per 2 elements)
__device__ __forceinline__ bf16x8 cvt8(float4 a, float4 b) {
    union { unsigned u[4]; bf16x8 v; } r;
    asm("v_cvt_pk_bf16_f32 %0, %1, %2" : "=v"(r.u[0]) : "v"(a.x), "v"(a.y));
    asm("v_cvt_pk_bf16_f32 %0, %1, %2" : "=v"(r.u[1]) : "v"(a.z), "v"(a.w));
    asm("v_cvt_pk_bf16_f32 %0, %1, %2" : "=v"(r.u[2]) : "v"(b.x), "v"(b.y));
    asm("v_cvt_pk_bf16_f32 %0, %1, %2" : "=v"(r.u[3]) : "v"(b.z), "v"(b.w));
    return r.v;
}

// async global->LDS, 16B per lane. LDS dest affine in lane (base + lane*16).
__device__ __forceinline__ void async_copy16(void* lds, const void* g) {
    __builtin_amdgcn_global_load_lds(
        (const __attribute__((address_space(1))) unsigned int*)g,
        (__attribute__((address_space(3))) unsigned int*)lds, 16, 0, 0);
}

// K0: W_enc (512x512 fp32) -> Wb bf16, per-K-slice swizzled layout.
// slice s = k>>5 (16 slices, 32KB each). 16B unit (j, q=(k>>3)&3) at
// u = 4*j + ((q + j) & 3): linear gload_lds image is conflict-minimal for the
// K2 B-frag ds_read_b128 pattern. (Proven in round 1.)
__global__ void k0_wenc_bf16(const float* __restrict__ W_enc, float* __restrict__ ws) {
    unsigned short* Wb = (unsigned short*)(ws + WS_WB);
    const int id = blockIdx.x * 256 + threadIdx.x;
    const int j = id >> 6, kc = id & 63;
    const int k = kc * 8;
    float4 a = *(const float4*)(W_enc + j * 512 + k);
    float4 b4 = *(const float4*)(W_enc + j * 512 + k + 4);
    ushort4 lo = {f2bf(a.x), f2bf(a.y), f2bf(a.z), f2bf(a.w)};
    ushort4 hi = {f2bf(b4.x), f2bf(b4.y), f2bf(b4.z), f2bf(b4.w)};
    const int s = kc >> 2, q = kc & 3;
    const int u = 4 * j + ((q + j) & 3);
    unsigned short* dst = Wb + s * 16384 + u * 8;
    *(ushort4*)(dst) = lo;
    *(ushort4*)(dst + 4) = hi;
}

// K1: embedded = emb[token] -> x[:, :256];  hW = h @ W_dec^T
__global__ void k1_embed_hw(const int* __restrict__ tok, const float* __restrict__ hidden,
                            const float* __restrict__ emb, const float* __restrict__ W_dec,
                            float* __restrict__ ws) {
    const int b = blockIdx.x, tid = threadIdx.x;
    __shared__ __align__(16) float sh[512];
    sh[tid]       = hidden[b * 512 + tid];
    sh[tid + 256] = hidden[b * 512 + tid + 256];
    const int t = tok[b];
    ws[WS_X + b * 768 + tid] = emb[t * 256 + tid];
    __syncthreads();
    for (int jr = tid; jr < 512; jr += 256) {
        const float* w = W_dec + jr * 512;
        float acc = 0.f;
        #pragma unroll 8
        for (int k = 0; k < 512; k += 4) {
            float4 wv = *(const float4*)(w + k);
            float4 hv = *(const float4*)(sh + k);
            acc += wv.x * hv.x + wv.y * hv.y + wv.z * hv.z + wv.w * hv.w;
        }
        ws[WS_HW + b * 512 + jr] = acc;
    }
}

// K2: scores via bf16 MFMA. Block tile M=64 t x N=512 j x K=512, BK=32, 16 steps.
// SAFE 2-phase (round-1-proven sync): per iter {stage next slice (async gload_lds),
// compute current, __syncthreads() (full vmcnt/lgkm drain)}. Stage latency overlaps
// compute; no counted-vmcnt ledger. A staged coalesced fp32 with XOR-preswizzled
// source (kq = ul^(row&7)); cvt_pk -> bf16 at frag read. B from K0-preswizzled Wb.
__global__ __launch_bounds__(256, 2)
void k2_scores(const float* __restrict__ enc, const float* __restrict__ v_attn,
               float* __restrict__ ws) {
    __shared__ __align__(16) unsigned char lds[81920];  // B[2][32KB] | A[2][8KB]
    char* ldsB = (char*)lds;
    char* ldsA = (char*)lds + 65536;
    float* spf = (float*)lds;  // epilogue overlay (B buf0, after final barrier)
    const unsigned short* Wb = (const unsigned short*)(ws + WS_WB);
    const int tid = threadIdx.x;
    const int lane = tid & 63, wv = tid >> 6;
    const int lane15 = lane & 15, quad = lane >> 4;
    const int t0 = blockIdx.x * 64, b = blockIdx.y;
    const int wn = wv * 128;
    const float* encA = enc + (size_t)(b * 2048 + t0) * 512;

    const int j0 = wn + lane15;
    const int rdBase = 64 * j0 + 16 * ((quad + j0) & 3);  // + nt*1024 (bytes)

    floatx4 acc[4][8];
    #pragma unroll
    for (int mt = 0; mt < 4; mt++)
        #pragma unroll
        for (int nt = 0; nt < 8; nt++) acc[mt][nt] = (floatx4){0.f, 0.f, 0.f, 0.f};

    auto stage = [&](int buf, int slice) {
        // A tile 64x32 fp32 (8KB): source preswizzled kq = ul ^ (row&7)
        #pragma unroll
        for (int q8 = 0; q8 < 2; ++q8) {
            int f = tid + 256 * q8;
            int row = f >> 3, ul = f & 7;
            int kq = ul ^ (row & 7);
            async_copy16(ldsA + buf * 8192 + f * 16,
                         (const char*)(encA + (size_t)row * 512 + slice * 32 + kq * 4));
        }
        // B tile 512x32 bf16 (32KB): linear copy of K0-preswizzled slice
        const char* gsB = (const char*)(Wb + slice * 16384);
        #pragma unroll
        for (int q8 = 0; q8 < 8; ++q8)
            async_copy16(ldsB + buf * 32768 + q8 * 4096 + tid * 16, gsB + q8 * 4096 + tid * 16);
    };

    auto compute = [&](int buf) {
        const char* bA = ldsA + buf * 8192;
        const char* bB = ldsB + buf * 32768;
        bf16x8 af[4];
        #pragma unroll
        for (int mt = 0; mt < 4; ++mt) {
            int row = mt * 16 + lane15, x = row & 7;
            float4 lo = *(const float4*)(bA + row * 128 + (((2 * quad) ^ x) * 16));
            float4 hi = *(const float4*)(bA + row * 128 + (((2 * quad + 1) ^ x) * 16));
            af[mt] = cvt8(lo, hi);
        }
        #pragma unroll
        for (int nt = 0; nt < 8; ++nt) {
            bf16x8 bfr = *(const bf16x8*)(bB + rdBase + nt * 1024);
            #pragma unroll
            for (int mt = 0; mt < 4; ++mt)
                acc[mt][nt] = __builtin_amdgcn_mfma_f32_16x16x32_bf16(af[mt], bfr, acc[mt][nt], 0, 0, 0);
        }
    };

    stage(0, 0);
    __syncthreads();  // slice0 resident (full drain)
    for (int t = 0; t < 16; ++t) {
        if (t < 15) stage((t + 1) & 1, t + 1);   // async, overlaps compute below
        __builtin_amdgcn_sched_barrier(0);        // pin: issue loads before compute
        compute(t & 1);
        __syncthreads();  // drains stage -> next slice resident; read-done for overwrite
    }

    // epilogue: tanh + v-dot + quad reduce + cross-wave LDS reduce
    float vj[8], hwj[8];
    #pragma unroll
    for (int nt = 0; nt < 8; nt++) {
        int jg = wn + nt * 16 + lane15;
        vj[nt] = v_attn[jg];
        hwj[nt] = ws[WS_HW + b * 512 + jg];
    }
    #pragma unroll
    for (int mt = 0; mt < 4; mt++) {
        #pragma unroll
        for (int reg = 0; reg < 4; reg++) {
            int row = mt * 16 + quad * 4 + reg;
            float s = 0.f;
            #pragma unroll
            for (int nt = 0; nt < 8; nt++)
                s += vj[nt] * fast_tanh(acc[mt][nt][reg] + hwj[nt]);
            #pragma unroll
            for (int off = 8; off; off >>= 1) s += __shfl_xor(s, off);
            if (lane15 == 0) spf[wv * 64 + row] = s;
        }
    }
    __syncthreads();
    if (tid < 64)
        ws[WS_SC + b * 2048 + t0 + tid] = spf[tid] + spf[64 + tid] + spf[128 + tid] + spf[192 + tid];
}

// K3: softmax over T per b; writes attn to d_out
__global__ void k3_softmax(const float* __restrict__ ws, float* __restrict__ out) {
    const int b = blockIdx.x, tid = threadIdx.x;
    const float* s0 = ws + WS_SC + b * 2048;
    float sv[8];
    float m = -1e30f;
    #pragma unroll
    for (int i = 0; i < 8; i++) {
        int t = tid + 256 * i;
        sv[i] = s0[t];
        m = fmaxf(m, sv[i]);
    }
    #pragma unroll
    for (int o = 32; o; o >>= 1) m = fmaxf(m, __shfl_xor(m, o, 64));
    __shared__ float red[4], red2[4];
    if ((tid & 63) == 0) red[tid >> 6] = m;
    __syncthreads();
    m = fmaxf(fmaxf(red[0], red[1]), fmaxf(red[2], red[3]));
    float sum = 0.f;
    #pragma unroll
    for (int i = 0; i < 8; i++) { sv[i] = __expf(sv[i] - m); sum += sv[i]; }
    #pragma unroll
    for (int o = 32; o; o >>= 1) sum += __shfl_xor(sum, o, 64);
    if ((tid & 63) == 0) red2[tid >> 6] = sum;
    __syncthreads();
    sum = red2[0] + red2[1] + red2[2] + red2[3];
    const float inv = 1.f / sum;
    #pragma unroll
    for (int i = 0; i < 8; i++) {
        int t = tid + 256 * i;
        out[ATTN_OFF + b * 2048 + t] = sv[i] * inv;
    }
}

// K4: context partials over t-chunks of 128
__global__ void k4_ctx(const float* __restrict__ enc, const float* __restrict__ attn_out,
                       float* __restrict__ ws) {
    const int ts = blockIdx.x, b = blockIdx.y, tid = threadIdx.x;
    const float* attn = attn_out + ATTN_OFF + b * 2048 + ts * 128;
    const float* ep = enc + (size_t)(b * 2048 + ts * 128) * 512 + tid * 2;
    float2 acc = {0.f, 0.f};
    #pragma unroll 4
    for (int tt = 0; tt < 128; tt++) {
        float a = attn[tt];
        float2 e = *(const float2*)(ep + (size_t)tt * 512);
        acc.x += a * e.x;
        acc.y += a * e.y;
    }
    *(float2*)(ws + WS_CTXP + (ts * 64 + b) * 512 + tid * 2) = acc;
}

// K4b: reduce 16 context partials -> x[:,256:768] and x2[:,512:1024] (fp32)
__global__ void k4b_ctx_reduce(float* __restrict__ ws) {
    const int idx = blockIdx.x * 256 + threadIdx.x;
    const int b = idx >> 9, h = idx & 511;
    float s = 0.f;
    #pragma unroll
    for (int c = 0; c < 16; c++) s += ws[WS_CTXP + c * (B_SZ * 512) + b * 512 + h];
    ws[WS_X + b * 768 + 256 + h] = s;
    ws[WS_X2 + b * 1024 + 512 + h] = s;
}

// K5: gate partials (fp32 register-tiled GEMM, small: 64x2048x1280)
__global__ __launch_bounds__(256, 2)
void k5_gates(const float* __restrict__ hidden, const float* __restrict__ W_ih,
              const float* __restrict__ W_hh, float* __restrict__ ws) {
    __shared__ __align__(16) float Wg[128 * 12];
    __shared__ __align__(16) float Zs[64 * 8];
    const int tid = threadIdx.x;
    const int jb = tid & 31, tg = tid >> 5;
    const int g0 = blockIdx.x * 128;
    const int kc = blockIdx.y;
    const int kbase = kc * 160;
    const float* xp = ws + WS_X;

    float acc[8][4];
    #pragma unroll
    for (int r = 0; r < 8; r++)
        #pragma unroll
        for (int j = 0; j < 4; j++) acc[r][j] = 0.f;

    for (int kt0 = 0; kt0 < 160; kt0 += 8) {
        const int kt = kbase + kt0;
        __syncthreads();
        {
            int row = tid >> 1, kq = tid & 1;
            int k = kt + kq * 4;
            const float* src = (k < 768) ? (W_ih + (g0 + row) * 768 + k)
                                         : (W_hh + (g0 + row) * 512 + (k - 768));
            *(float4*)(Wg + row * 12 + kq * 4) = *(const float4*)src;
        }
        if (tid < 128) {
            int row = tid >> 1, kq = tid & 1;
            int k = kt + kq * 4;
            const float* src = (k < 768) ? (xp + row * 768 + k)
                                         : (hidden + row * 512 + (k - 768));
            *(float4*)(Zs + row * 8 + kq * 4) = *(const float4*)src;
        }
        __syncthreads();

        float er[8][8];
        #pragma unroll
        for (int r = 0; r < 8; r++) {
            float4 a = *(const float4*)(Zs + (tg * 8 + r) * 8);
            float4 c = *(const float4*)(Zs + (tg * 8 + r) * 8 + 4);
            er[r][0] = a.x; er[r][1] = a.y; er[r][2] = a.z; er[r][3] = a.w;
            er[r][4] = c.x; er[r][5] = c.y; er[r][6] = c.z; er[r][7] = c.w;
        }
        #pragma unroll
        for (int jj = 0; jj < 4; jj++) {
            const float* wr = Wg + (jb + 32 * jj) * 12;
            float4 w0 = *(const float4*)(wr);
            float4 w1 = *(const float4*)(wr + 4);
            float w[8] = {w0.x, w0.y, w0.z, w0.w, w1.x, w1.y, w1.z, w1.w};
            #pragma unroll
            for (int r = 0; r < 8; r++)
                #pragma unroll
                for (int k = 0; k < 8; k++) acc[r][jj] += er[r][k] * w[k];
        }
    }
    #pragma unroll
    for (int jj = 0; jj < 4; jj++)
        #pragma unroll
        for (int r = 0; r < 8; r++)
            ws[WS_GP + kc * (B_SZ * 2048) + (tg * 8 + r) * 2048 + g0 + jb + 32 * jj] = acc[r][jj];
}

// K5b: sum gate partials + biases, LSTM pointwise; h_new -> out + x2 (fp32)
__global__ void k5b_lstm(const float* __restrict__ cell, const float* __restrict__ b_ih,
                         const float* __restrict__ b_hh, float* __restrict__ ws,
                         float* __restrict__ out) {
    const int e = blockIdx.x * 256 + threadIdx.x;
    const int b = e >> 9, hh = e & 511;
    float g4[4];
    #pragma unroll
    for (int q = 0; q < 4; q++) {
        float s = b_ih[q * 512 + hh] + b_hh[q * 512 + hh];
        #pragma unroll
        for (int c = 0; c < 8; c++)
            s += ws[WS_GP + c * (B_SZ * 2048) + b * 2048 + q * 512 + hh];
        g4[q] = s;
    }
    const float ig = fast_sigmoid(g4[0]);
    const float fg = fast_sigmoid(g4[1]);
    const float gg = fast_tanh(g4[2]);
    const float og = fast_sigmoid(g4[3]);
    const float c_old = cell[b * 512 + hh];
    const float c_new = fg * c_old + ig * gg;
    const float h_new = og * fast_tanh(c_new);
    out[H_OFF + b * 512 + hh] = h_new;
    out[C_OFF + b * 512 + hh] = c_new;
    ws[WS_X2 + b * 1024 + hh] = h_new;
}

// K6: logits via bf16 MFMA, same safe 2-phase template as K2.
// Tile M=64 b x N=128 v x K=1024, BK=32, 32 steps. 391 blocks, 48KB LDS,
// 3 blocks/CU for TLP hiding of the W_out HBM stream. Both operands staged
// fp32 via gload_lds with XOR-preswizzled source; cvt_pk at frag read.
__global__ __launch_bounds__(256, 3)
void k6_logits(const float* __restrict__ W_out, const float* __restrict__ b_out,
               const float* __restrict__ ws, float* __restrict__ out) {
    __shared__ __align__(16) unsigned char lds[49152];  // W[2][16KB] | X[2][8KB]
    char* ldsW = (char*)lds;
    char* ldsX = (char*)lds + 32768;
    const float* x2f = ws + WS_X2;
    const int tid = threadIdx.x;
    const int lane = tid & 63, wv = tid >> 6;
    const int lane15 = lane & 15, quad = lane >> 4;
    const int v0 = blockIdx.x * 128;
    const int wn = wv * 32;

    floatx4 acc[4][2];
    #pragma unroll
    for (int mt = 0; mt < 4; mt++)
        #pragma unroll
        for (int nt = 0; nt < 2; nt++) acc[mt][nt] = (floatx4){0.f, 0.f, 0.f, 0.f};

    auto stage = [&](int buf, int slice) {
        // X tile 64x32 fp32 (8KB): source preswizzled kq = ul ^ (row&7)
        #pragma unroll
        for (int q8 = 0; q8 < 2; ++q8) {
            int f = tid + 256 * q8;
            int row = f >> 3, ul = f & 7;
            int kq = ul ^ (row & 7);
            async_copy16(ldsX + buf * 8192 + f * 16,
                         (const char*)(x2f + row * 1024 + slice * 32 + kq * 4));
        }
        // W tile 128x32 fp32 (16KB): source preswizzled kq = ul ^ (row&7)
        #pragma unroll
        for (int q8 = 0; q8 < 4; ++q8) {
            int f = tid + 256 * q8;
            int row = f >> 3, ul = f & 7;
            int v = v0 + row; if (v > V_SZ - 1) v = V_SZ - 1;
            int kq = ul ^ (row & 7);
            async_copy16(ldsW + buf * 16384 + f * 16,
                         (const char*)(W_out + (size_t)v * 1024 + slice * 32 + kq * 4));
        }
    };

    auto compute = [&](int buf) {
        const char* bX = ldsX + buf * 8192;
        const char* bW = ldsW + buf * 16384;
        bf16x8 af[4];
        #pragma unroll
        for (int mt = 0; mt < 4; ++mt) {
            int row = mt * 16 + lane15, x = row & 7;
            float4 lo = *(const float4*)(bX + row * 128 + (((2 * quad) ^ x) * 16));
            float4 hi = *(const float4*)(bX + row * 128 + (((2 * quad + 1) ^ x) * 16));
            af[mt] = cvt8(lo, hi);
        }
        #pragma unroll
        for (int nt = 0; nt < 2; ++nt) {
            int row = wn + nt * 16 + lane15, x = row & 7;
            float4 lo = *(const float4*)(bW + row * 128 + (((2 * quad) ^ x) * 16));
            float4 hi = *(const float4*)(bW + row * 128 + (((2 * quad + 1) ^ x) * 16));
            bf16x8 bfr = cvt8(lo, hi);
            #pragma unroll
            for (int mt = 0; mt < 4; ++mt)
                acc[mt][nt] = __builtin_amdgcn_mfma_f32_16x16x32_bf16(af[mt], bfr, acc[mt][nt], 0, 0, 0);
        }
    };

    stage(0, 0);
    __syncthreads();
    for (int t = 0; t < 32; ++t) {
        if (t < 31) stage((t + 1) & 1, t + 1);
        __builtin_amdgcn_sched_barrier(0);
        compute(t & 1);
        __syncthreads();
    }

    #pragma unroll
    for (int nt = 0; nt < 2; nt++) {
        const int v = v0 + wn + nt * 16 + lane15;
        if (v < V_SZ) {
            const float bo = b_out[v];
            #pragma unroll
            for (int mt = 0; mt < 4; mt++)
                #pragma unroll
                for (int reg = 0; reg < 4; reg++) {
                    const int br = mt * 16 + quad * 4 + reg;
                    out[br * V_SZ + v] = acc[mt][nt][reg] + bo;
                }
        }
    }
}

extern "C" void kernel_launch(void* const* d_in, const int* in_sizes, int n_in,
                              void* d_out, int out_size, void* d_ws, size_t ws_size,
                              hipStream_t stream) {
    (void)in_sizes; (void)n_in; (void)out_size; (void)ws_size;
    const int*   tok    = (const int*)d_in[0];
    const float* hidden = (const float*)d_in[1];
    const float* cell   = (const float*)d_in[2];
    const float* enc    = (const float*)d_in[3];
    const float* emb    = (const float*)d_in[4];
    const float* W_enc  = (const float*)d_in[5];
    const float* W_dec  = (const float*)d_in[6];
    const float* v_attn = (const float*)d_in[7];
    const float* W_ih   = (const float*)d_in[8];
    const float* W_hh   = (const float*)d_in[9];
    const float* b_ih   = (const float*)d_in[10];
    const float* b_hh   = (const float*)d_in[11];
    const float* W_out  = (const float*)d_in[12];
    const float* b_out  = (const float*)d_in[13];
    float* out = (float*)d_out;
    float* ws  = (float*)d_ws;

    k0_wenc_bf16<<<dim3(128), dim3(256), 0, stream>>>(W_enc, ws);
    k1_embed_hw<<<dim3(64), dim3(256), 0, stream>>>(tok, hidden, emb, W_dec, ws);
    k2_scores<<<dim3(32, 64), dim3(256), 0, stream>>>(enc, v_attn, ws);
    k3_softmax<<<dim3(64), dim3(256), 0, stream>>>(ws, out);
    k4_ctx<<<dim3(16, 64), dim3(256), 0, stream>>>(enc, out, ws);
    k4b_ctx_reduce<<<dim3(128), dim3(256), 0, stream>>>(ws);
    k5_gates<<<dim3(16, 8), dim3(256), 0, stream>>>(hidden, W_ih, W_hh, ws);
    k5b_lstm<<<dim3(128), dim3(256), 0, stream>>>(cell, b_ih, b_hh, ws, out);
    k6_logits<<<dim3(391), dim3(256), 0, stream>>>(W_out, b_out, ws, out);
}